// Round 17
// baseline (174.469 us; speedup 1.0000x reference)
//
#include <hip/hip_runtime.h>

typedef __attribute__((ext_vector_type(8))) short short8;
typedef __attribute__((ext_vector_type(4))) short s16x4;
typedef __attribute__((ext_vector_type(4))) float f32x4;
typedef __attribute__((ext_vector_type(2))) unsigned u32x2;
typedef __attribute__((ext_vector_type(2))) __fp16 h2v;      // cvt_pkrtz result type
typedef __attribute__((ext_vector_type(8))) _Float16 half8;  // f16 MFMA operand

static __device__ __forceinline__ short f2bf(float x) {
  union { float f; unsigned u; } v; v.f = x;
  unsigned r = (v.u + 0x7fffu + ((v.u >> 16) & 1u)) >> 16;
  return (short)r;
}
static __device__ __forceinline__ short f2h(float x) {
  h2v p = __builtin_amdgcn_cvt_pkrtz(x, 0.f);
  union { h2v v; unsigned u; } c; c.v = p;
  return (short)(c.u & 0xffffu);
}
// packed f32x2 -> bf16x2 (RNE), 1 VALU op
static __device__ __forceinline__ unsigned cvtpk(float lo, float hi) {
  unsigned r;
  asm("v_cvt_pk_bf16_f32 %0, %1, %2" : "=v"(r) : "v"(lo), "v"(hi));
  return r;
}

// async 16B global -> LDS (dest: wave-uniform base + lane*16; src: per-lane)
static __device__ __forceinline__ void gld16(const short* g, short* l) {
  __builtin_amdgcn_global_load_lds(
      (const __attribute__((address_space(1))) unsigned*)g,
      (__attribute__((address_space(3))) unsigned*)l, 16, 0, 0);
}

// ---------------- prep: all conversions in one launch ----------------
static __device__ __forceinline__ void conv8(const float* __restrict__ src,
                                             short* __restrict__ dst, int i,
                                             float scale) {
  const f32x4* s = (const f32x4*)(src + (long)i * 8);
  f32x4 a = s[0], b = s[1];
  short8 o;
  o[0] = f2bf(a[0] * scale); o[1] = f2bf(a[1] * scale);
  o[2] = f2bf(a[2] * scale); o[3] = f2bf(a[3] * scale);
  o[4] = f2bf(b[0] * scale); o[5] = f2bf(b[1] * scale);
  o[6] = f2bf(b[2] * scale); o[7] = f2bf(b[3] * scale);
  *(short8*)(dst + (long)i * 8) = o;
}

__global__ __launch_bounds__(256) void prep(
    const float* __restrict__ Q, const float* __restrict__ KV,
    const float* __restrict__ Wq, const float* __restrict__ Wk,
    const float* __restrict__ Wv, const float* __restrict__ Wp,
    const float* __restrict__ bq,
    short* __restrict__ Qb, short* __restrict__ KVb,
    short* __restrict__ Wqb, short* __restrict__ Wkb,
    short* __restrict__ Wvb, short* __restrict__ Wpb,
    float* __restrict__ bqs) {
  const int blk = blockIdx.x, tid = threadIdx.x;
  if (blk < 2048) {
    conv8(Q, Qb, blk * 256 + tid, 1.f);
  } else if (blk < 4096) {
    conv8(KV, KVb, (blk - 2048) * 256 + tid, 1.f);
  } else if (blk < 4608) {
    conv8(Wq, Wqb, (blk - 4096) * 256 + tid, 0.125f);   // fold 1/8 into Wq
  } else if (blk < 5120) {
    conv8(Wk, Wkb, (blk - 4608) * 256 + tid, 1.f);
  } else if (blk < 5632) {
    conv8(Wv, Wvb, (blk - 5120) * 256 + tid, 1.f);
  } else if (blk < 6656) {
    // Wpb[o][g*64+d] = Wp[o][d*16+g]
    __shared__ float row[1024];
    const long o = blk - 5632;
    *(f32x4*)&row[tid * 4] = *(const f32x4*)(Wp + o * 1024 + tid * 4);
    __syncthreads();
    const int f0 = tid * 4;
    s16x4 t;
#pragma unroll
    for (int j = 0; j < 4; ++j) {
      int f = f0 + j;
      t[j] = f2bf(row[((f & 63) << 4) + (f >> 6)]);
    }
    *(s16x4*)(Wpb + o * 1024 + f0) = t;
  } else {
    int i = (blk - 6656) * 256 + tid;
    bqs[i] = bq[i] * 0.125f;                            // fold 1/8 into bq
  }
}

// ---------------- 128x128 GEMM core (BK=64, dbuf, global_load_lds) ----------------
// Sm: 32768-short flat LDS. 16-bit outputs bounce through LDS (stride 136) for
// coalesced 16B stores. omode 0: C[row*1024+col] (bf16); omode 1 (vt, FP16):
// C[col<<10 | t].
template <typename OutT>
static __device__ __forceinline__ void gemm_core(
    const short* __restrict__ A, const short* __restrict__ B,
    OutT* __restrict__ C, const float* __restrict__ bias,
    const float* __restrict__ resid, int bm, int bn, int omode,
    short* Sm) {
  const int tid = threadIdx.x, lane = tid & 63, wave = tid >> 6;
  const int fr = lane & 15, khi = lane >> 4;
  const int wr = wave >> 1, wc = wave & 1;

  f32x4 acc[4][4];
#pragma unroll
  for (int m = 0; m < 4; ++m)
#pragma unroll
    for (int n = 0; n < 4; ++n) acc[m][n] = (f32x4){0.f, 0.f, 0.f, 0.f};

  auto stage = [&](int buf, int k0) {
    short* Asb = Sm + buf * 16384;
    short* Bsb = Asb + 8192;
#pragma unroll
    for (int it = 0; it < 4; ++it) {
      int l = it * 256 + tid;
      int r = l >> 3, c = (l & 7) ^ (r & 7);
      gld16(A + (long)(bm + r) * 1024 + k0 + c * 8, &Asb[l * 8]);
      gld16(B + (long)(bn + r) * 1024 + k0 + c * 8, &Bsb[l * 8]);
    }
  };

  stage(0, 0);
  __syncthreads();
  int cur = 0;
  for (int k0 = 0; k0 < 1024; k0 += 64) {
    if (k0 < 960) stage(cur ^ 1, k0 + 64);
    const short* Asb = Sm + cur * 16384;
    const short* Bsb = Asb + 8192;
#pragma unroll
    for (int ks = 0; ks < 64; ks += 32) {
      const int cc = (ks >> 3) + khi;
      short8 af[4], bf[4];
#pragma unroll
      for (int m = 0; m < 4; ++m) {
        const int ar = wr * 64 + m * 16 + fr;
        af[m] = *(const short8*)&Asb[ar * 64 + ((cc ^ (ar & 7)) * 8)];
      }
#pragma unroll
      for (int n = 0; n < 4; ++n) {
        const int br = wc * 64 + n * 16 + fr;
        bf[n] = *(const short8*)&Bsb[br * 64 + ((cc ^ (br & 7)) * 8)];
      }
#pragma unroll
      for (int m = 0; m < 4; ++m)
#pragma unroll
        for (int n = 0; n < 4; ++n)
          acc[m][n] = __builtin_amdgcn_mfma_f32_16x16x32_bf16(af[m], bf[n],
                                                              acc[m][n], 0, 0, 0);
    }
    __syncthreads();
    cur ^= 1;
  }

  const int col0 = fr, row0 = khi * 4;
  if constexpr (sizeof(OutT) == 2) {
    // 16-bit output: LDS bounce -> coalesced 16B stores. omode 1 emits FP16.
#pragma unroll
    for (int m = 0; m < 4; ++m) {
#pragma unroll
      for (int n = 0; n < 4; ++n) {
        const int dgl = wc * 64 + n * 16 + col0;
        const float bi = bias[bn + dgl];
#pragma unroll
        for (int i = 0; i < 4; ++i) {
          const int tl = wr * 64 + m * 16 + row0 + i;
          const int a = (omode == 1) ? (dgl * 136 + tl) : (tl * 136 + dgl);
          const float vv = acc[m][n][i] + bi;
          Sm[a] = (omode == 1) ? f2h(vv) : f2bf(vv);
        }
      }
    }
    __syncthreads();
    short* Cs = (short*)C;
#pragma unroll
    for (int it = 0; it < 8; ++it) {
      const int ch = it * 256 + tid;          // 2048 chunks of 16B
      const int r = ch >> 4, cchunk = ch & 15;
      short8 v8 = *(const short8*)&Sm[r * 136 + cchunk * 8];
      long addr;
      if (omode == 0)
        addr = (long)(bm + r) * 1024 + bn + cchunk * 8;
      else
        addr = ((long)(bm >> 10) << 20) + ((long)(bn + r) << 10) + (bm & 1023) +
               cchunk * 8;
      *(short8*)(Cs + addr) = v8;
    }
  } else {
    // f32 output (pre): scalar path, 64B segments
#pragma unroll
    for (int m = 0; m < 4; ++m) {
#pragma unroll
      for (int n = 0; n < 4; ++n) {
        const int gcol = bn + wc * 64 + n * 16 + col0;
        const float bi = bias[gcol];
#pragma unroll
        for (int i = 0; i < 4; ++i) {
          const int grow = bm + wr * 64 + m * 16 + row0 + i;
          float v = acc[m][n][i] + bi;
          if (resid) v += resid[(long)grow * 1024 + gcol];
          C[(long)grow * 1024 + gcol] = v;
        }
      }
    }
  }
}

// three projections in one launch: seg 0: qb, 1: kb, 2: vt (fp16)
__global__ __launch_bounds__(256, 2) void proj_all(
    const short* __restrict__ Qb, const short* __restrict__ KVb,
    const short* __restrict__ Wqb, const short* __restrict__ Wkb,
    const short* __restrict__ Wvb,
    const float* __restrict__ bqs, const float* __restrict__ bk,
    const float* __restrict__ bv,
    short* __restrict__ qb, short* __restrict__ kb, short* __restrict__ vt) {
  __shared__ short Sm[32768];                // 64 KB
  int bid = blockIdx.x;
  int swz = (bid & 7) * 96 + (bid >> 3);     // 768 blocks, XCD-contiguous
  const int seg = swz >> 8, local = swz & 255;
  const int bm = (local >> 3) * 128, bn = (local & 7) * 128;
  if (seg == 0)
    gemm_core<short>(Qb, Wqb, qb, bqs, nullptr, bm, bn, 0, Sm);
  else if (seg == 1)
    gemm_core<short>(KVb, Wkb, kb, bk, nullptr, bm, bn, 0, Sm);
  else
    gemm_core<short>(KVb, Wvb, vt, bv, nullptr, bm, bn, 1, Sm);
}

// final GEMM: pre = at @ Wpb^T + bp + Q
__global__ __launch_bounds__(256, 2) void out_gemm(
    const short* __restrict__ at, const short* __restrict__ Wpb,
    const float* __restrict__ bp, const float* __restrict__ Q,
    float* __restrict__ pre) {
  __shared__ short Sm[32768];
  int bid = blockIdx.x;
  int swz = (bid & 7) * 32 + (bid >> 3);     // 256 blocks
  const int bm = (swz >> 3) * 128, bn = (swz & 7) * 128;
  gemm_core<float>(at, Wpb, pre, bp, Q, bm, bn, 0, Sm);
}

// ---------------- fused attention v17: single QK^T, Pfull fp16-resident ----------------
// 512 thr (8 waves) per (z, 64 q-rows). Phase A: QK^T once per 64-key tile
// (K dbuf in Ks), exp -> Pfull (FP16 via pkrtz), sums accumulated from the
// ROUNDED values (self-consistent normalization) -> invL.
// Phase C: PV (f16 MFMA, V fp16 dbuf reusing Ks) + interleaved normalized
// score writes from Pfull; pacc scaled by invL at the end; at via Ks-bounce.
__global__ __launch_bounds__(512, 1) void fused_attn(
    const short* __restrict__ qb,   // [4][1024][1024] bf16, feat = g*64+d (x1/8)
    const short* __restrict__ kb,   // [4][1024][1024] bf16, feat = g*64+d
    const short* __restrict__ vt,   // [4][1024][1024] FP16, vt[b][d*16+g][t]
    float* __restrict__ scores,     // [64][1024][1024] f32
    short* __restrict__ at) {       // [4][1024][1024] bf16, feat = g*64+d
  constexpr int LPF = 1032;          // pad: 2064B row stride -> 4-bank step
  __shared__ short Pfull[64 * LPF];  // 129 KB (fp16 payload)
  __shared__ short Ks[2][64 * 64];   // 16 KB: K dbuf -> V dbuf -> at bounce
  __shared__ float SxL[128];
  __shared__ float invL[64];

  int bid = blockIdx.x;
  bid = (bid & 7) * 128 + (bid >> 3);     // 8 z's per XCD
  const int z = bid >> 4, b = z >> 4, g = z & 15;
  const int q0 = (bid & 15) * 64;

  const int tid = threadIdx.x, lane = tid & 63, w = tid >> 6;
  const int fr = lane & 15, khi = lane >> 4;
  const long bqk = (long)b << 20;
  const int rg = w >> 1, kh = w & 1;      // A: (rowgroup, key-half); C: (rowgroup, d-half)

  const short* qrow = qb + bqk + (long)(q0 + rg * 16 + fr) * 1024 + g * 64 + khi * 8;
  const short8 aq0 = *(const short8*)qrow;
  const short8 aq1 = *(const short8*)(qrow + 32);
  const short* kgp = kb + bqk + g * 64;
  const short* vgp = vt + bqk;

  auto stageK = [&](int buf, int t0) {
    int r = tid >> 3, c = (tid & 7) ^ ((tid >> 5) & 7);   // xor key (r>>2)&7
    gld16(kgp + (long)(t0 + r) * 1024 + c * 8, &Ks[buf][tid * 8]);
  };
  auto stageV = [&](int buf, int t0) {
    int r = tid >> 3, c = (tid & 7) ^ (r & 7);            // xor key r&7
    gld16(vgp + ((long)(r * 16 + g) << 10) + t0 + c * 8, &Ks[buf][tid * 8]);
  };

  const int xk = fr >> 1;                 // = (r2>>2)&7 for r2 = kh*32 + fr*2 + nf

  // ---- phase A: QK^T once; exp -> Pfull (fp16); self-consistent sums ----
  float s4[4] = {0.f, 0.f, 0.f, 0.f};
  stageK(0, 0);
  __syncthreads();
  int cur = 0;
  for (int t0 = 0; t0 < 1024; t0 += 64) {
    if (t0 < 960) stageK(cur ^ 1, t0 + 64);
    f32x4 sacc[2];
    sacc[0] = (f32x4){0.f, 0.f, 0.f, 0.f};
    sacc[1] = (f32x4){0.f, 0.f, 0.f, 0.f};
#pragma unroll
    for (int nf = 0; nf < 2; ++nf) {
      const int r2 = kh * 32 + fr * 2 + nf;
      short8 b0 = *(const short8*)&Ks[cur][r2 * 64 + ((khi ^ xk) * 8)];
      short8 b1 = *(const short8*)&Ks[cur][r2 * 64 + (((khi + 4) ^ xk) * 8)];
      sacc[nf] = __builtin_amdgcn_mfma_f32_16x16x32_bf16(aq0, b0, sacc[nf], 0, 0, 0);
      sacc[nf] = __builtin_amdgcn_mfma_f32_16x16x32_bf16(aq1, b1, sacc[nf], 0, 0, 0);
    }
#pragma unroll
    for (int i = 0; i < 4; ++i) {
      float o0 = __expf(sacc[0][i]);
      float o1 = __expf(sacc[1][i]);
      h2v pk = __builtin_amdgcn_cvt_pkrtz(o0, o1);
      union { h2v v; unsigned u; } c; c.v = pk;
      *(unsigned*)&Pfull[(rg * 16 + khi * 4 + i) * LPF + t0 + kh * 32 + fr * 2] = c.u;
      s4[i] += (float)pk[0] + (float)pk[1];   // sum of ROUNDED numerators
    }
    __syncthreads();
    cur ^= 1;
  }
  // sums: reduce over fr, combine kh pair via SxL
#pragma unroll
  for (int i = 0; i < 4; ++i) {
    float s = s4[i];
    s += __shfl_xor(s, 1);
    s += __shfl_xor(s, 2);
    s += __shfl_xor(s, 4);
    s += __shfl_xor(s, 8);
    s4[i] = s;
  }
  if (fr == 0) {
#pragma unroll
    for (int i = 0; i < 4; ++i) SxL[w * 16 + khi * 4 + i] = s4[i];
  }
  __syncthreads();
  if (tid < 64) {
    const int r16 = tid & 15, rgw = (tid >> 4) * 2;
    invL[tid] = 1.f / (SxL[rgw * 16 + r16] + SxL[(rgw + 1) * 16 + r16]);
  }
  __syncthreads();

  // ---- phase C: PV (f16 MFMA, V dbuf in Ks) + interleaved score writes ----
  f32x4 pacc[2];
  pacc[0] = (f32x4){0.f, 0.f, 0.f, 0.f};
  pacc[1] = (f32x4){0.f, 0.f, 0.f, 0.f};
  float iv[4];
#pragma unroll
  for (int i = 0; i < 4; ++i) iv[i] = invL[rg * 16 + khi * 4 + i];
  const float ivb = invL[tid >> 3];
  const int srow = tid >> 3, sc8 = tid & 7;

  stageV(0, 0);
  __syncthreads();
  cur = 0;
  for (int tv = 0; tv < 1024; tv += 64) {
    if (tv < 960) stageV(cur ^ 1, tv + 64);
#pragma unroll
    for (int kk = 0; kk < 2; ++kk) {
      half8 ap = *(const half8*)&Pfull[(rg * 16 + fr) * LPF + tv + kk * 32 + khi * 8];
      const int cc = kk * 4 + khi;
#pragma unroll
      for (int nv = 0; nv < 2; ++nv) {
        const int dr = kh * 32 + nv * 16 + fr;
        half8 bvv = *(const half8*)&Ks[cur][dr * 64 + ((cc ^ (dr & 7)) * 8)];
        pacc[nv] = __builtin_amdgcn_mfma_f32_16x16x32_f16(ap, bvv, pacc[nv], 0, 0, 0);
      }
    }
    // normalized score slice for this key tile (hidden under MFMA latency)
    {
      half8 hv = *(const half8*)&Pfull[srow * LPF + tv + sc8 * 8];
      f32x4 oa, ob;
#pragma unroll
      for (int j = 0; j < 4; ++j) {
        oa[j] = (float)hv[j] * ivb;
        ob[j] = (float)hv[j + 4] * ivb;
      }
      float* sp = &scores[((long)z << 20) + ((long)(q0 + srow) << 10) + tv + sc8 * 8];
      __builtin_nontemporal_store(oa, (f32x4*)sp);
      __builtin_nontemporal_store(ob, (f32x4*)(sp + 4));
    }
    __syncthreads();
    cur ^= 1;
  }

  // scale by inv, bounce via Ks, coalesced at stores
  short* bounce = (short*)Ks;
#pragma unroll
  for (int nv = 0; nv < 2; ++nv)
#pragma unroll
    for (int i = 0; i < 4; ++i)
      bounce[(rg * 16 + khi * 4 + i) * 72 + kh * 32 + nv * 16 + fr] =
          f2bf(pacc[nv][i] * iv[i]);
  __syncthreads();
  {
    const int row = tid >> 3, fc = tid & 7;
    s16x4 lo = *(const s16x4*)&bounce[row * 72 + fc * 8];
    s16x4 hi = *(const s16x4*)&bounce[row * 72 + fc * 8 + 4];
    short8 v8;
    v8[0] = lo[0]; v8[1] = lo[1]; v8[2] = lo[2]; v8[3] = lo[3];
    v8[4] = hi[0]; v8[5] = hi[1]; v8[6] = hi[2]; v8[7] = hi[3];
    *(short8*)(at + bqk + ((long)(q0 + row) << 10) + g * 64 + fc * 8) = v8;
  }
}

// one wave per 1024-elem row
__global__ __launch_bounds__(256) void layernorm_rows(const float* __restrict__ X,
                                                      const float* __restrict__ gamma,
                                                      const float* __restrict__ beta,
                                                      float* __restrict__ O) {
  const int row = blockIdx.x * 4 + (threadIdx.x >> 6);
  const int lane = threadIdx.x & 63;
  const float* x = X + (long)row * 1024 + lane * 4;
  f32x4 v[4];
  float s = 0.f, sq = 0.f;
#pragma unroll
  for (int j = 0; j < 4; ++j) {
    v[j] = *(const f32x4*)(x + j * 256);
#pragma unroll
    for (int e = 0; e < 4; ++e) {
      s += v[j][e];
      sq += v[j][e] * v[j][e];
    }
  }
#pragma unroll
  for (int off = 32; off; off >>= 1) {
    s += __shfl_xor(s, off);
    sq += __shfl_xor(sq, off);
  }
  const float mu = s * (1.f / 1024.f);
  const float var = sq * (1.f / 1024.f) - mu * mu;
  const float rstd = rsqrtf(var + 1e-5f);
  float* o = O + (long)row * 1024 + lane * 4;
#pragma unroll
  for (int j = 0; j < 4; ++j) {
    f32x4 g = *(const f32x4*)(gamma + lane * 4 + j * 256);
    f32x4 be = *(const f32x4*)(beta + lane * 4 + j * 256);
    f32x4 r;
#pragma unroll
    for (int e = 0; e < 4; ++e) r[e] = (v[j][e] - mu) * rstd * g[e] + be[e];
    *(f32x4*)(o + j * 256) = r;
  }
}

extern "C" void kernel_launch(void* const* d_in, const int* in_sizes, int n_in,
                              void* d_out, int out_size, void* d_ws, size_t ws_size,
                              hipStream_t stream) {
  const float* Q = (const float*)d_in[0];
  const float* KV = (const float*)d_in[1];
  const float* Wq = (const float*)d_in[2];
  const float* bq = (const float*)d_in[3];
  const float* Wk = (const float*)d_in[4];
  const float* bk = (const float*)d_in[5];
  const float* Wv = (const float*)d_in[6];
  const float* bv = (const float*)d_in[7];
  const float* Wp = (const float*)d_in[8];
  const float* bp = (const float*)d_in[9];
  const float* gamma = (const float*)d_in[10];
  const float* beta = (const float*)d_in[11];

  float* out = (float*)d_out;                       // [4M] f32
  float* scores = out + (long)4 * 1024 * 1024;      // [64M] f32

  char* ws = (char*)d_ws;
  short* Wqb = (short*)(ws);                        // 2MB each
  short* Wkb = (short*)(ws + (2L << 20));
  short* Wvb = (short*)(ws + (4L << 20));
  short* Wpb = (short*)(ws + (6L << 20));           // permuted columns
  short* qb  = (short*)(ws + (8L << 20));           // 8MB (pre-scaled by 1/8)
  short* kb  = (short*)(ws + (16L << 20));          // 8MB
  short* vt  = (short*)(ws + (24L << 20));          // 8MB (FP16)
  short* at  = (short*)(ws + (32L << 20));          // 8MB, feat = g*64+d
  float* pre = (float*)(ws + (40L << 20));          // 16MB (written after attn)
  short* Qb  = (short*)(ws + (40L << 20));          // 8MB  (dead before pre)
  short* KVb = (short*)(ws + (48L << 20));          // 8MB  (dead before pre)
  float* bqs = (float*)(ws + (56L << 20));          // 4KB
  (void)ws_size; (void)in_sizes; (void)n_in; (void)out_size;

  // 1) all conversions, one launch
  prep<<<6660, 256, 0, stream>>>(Q, KV, Wq, Wk, Wv, Wp, bq,
                                 Qb, KVb, Wqb, Wkb, Wvb, Wpb, bqs);

  // 2) three projections, one launch
  proj_all<<<768, 256, 0, stream>>>(Qb, KVb, Wqb, Wkb, Wvb, bqs, bk, bv,
                                    qb, kb, vt);

  // 3) fused attention: scores (d_out) + at
  fused_attn<<<1024, 512, 0, stream>>>(qb, kb, vt, scores, at);

  // 4) pre = at @ Wpb^T + bp + Q
  out_gemm<<<256, 256, 0, stream>>>(at, Wpb, bp, Q, pre);

  // 5) LayerNorm -> out
  layernorm_rows<<<1024, 256, 0, stream>>>(pre, gamma, beta, out);
}

// Round 18
// 164.722 us; speedup vs baseline: 1.0592x; 1.0592x over previous
//
#include <hip/hip_runtime.h>

typedef __attribute__((ext_vector_type(8))) short short8;
typedef __attribute__((ext_vector_type(4))) short s16x4;
typedef __attribute__((ext_vector_type(4))) float f32x4;
typedef __attribute__((ext_vector_type(2))) unsigned u32x2;

static __device__ __forceinline__ short f2bf(float x) {
  union { float f; unsigned u; } v; v.f = x;
  unsigned r = (v.u + 0x7fffu + ((v.u >> 16) & 1u)) >> 16;
  return (short)r;
}
// packed f32x2 -> bf16x2 (RNE), 1 VALU op
static __device__ __forceinline__ unsigned cvtpk(float lo, float hi) {
  unsigned r;
  asm("v_cvt_pk_bf16_f32 %0, %1, %2" : "=v"(r) : "v"(lo), "v"(hi));
  return r;
}

// async 16B global -> LDS (dest: wave-uniform base + lane*16; src: per-lane)
static __device__ __forceinline__ void gld16(const short* g, short* l) {
  __builtin_amdgcn_global_load_lds(
      (const __attribute__((address_space(1))) unsigned*)g,
      (__attribute__((address_space(3))) unsigned*)l, 16, 0, 0);
}

// ---------------- prep: all conversions in one launch ----------------
static __device__ __forceinline__ void conv8(const float* __restrict__ src,
                                             short* __restrict__ dst, int i,
                                             float scale) {
  const f32x4* s = (const f32x4*)(src + (long)i * 8);
  f32x4 a = s[0], b = s[1];
  short8 o;
  o[0] = f2bf(a[0] * scale); o[1] = f2bf(a[1] * scale);
  o[2] = f2bf(a[2] * scale); o[3] = f2bf(a[3] * scale);
  o[4] = f2bf(b[0] * scale); o[5] = f2bf(b[1] * scale);
  o[6] = f2bf(b[2] * scale); o[7] = f2bf(b[3] * scale);
  *(short8*)(dst + (long)i * 8) = o;
}

__global__ __launch_bounds__(256) void prep(
    const float* __restrict__ Q, const float* __restrict__ KV,
    const float* __restrict__ Wq, const float* __restrict__ Wk,
    const float* __restrict__ Wv, const float* __restrict__ Wp,
    const float* __restrict__ bq,
    short* __restrict__ Qb, short* __restrict__ KVb,
    short* __restrict__ Wqb, short* __restrict__ Wkb,
    short* __restrict__ Wvb, short* __restrict__ Wpb,
    float* __restrict__ bqs) {
  const int blk = blockIdx.x, tid = threadIdx.x;
  if (blk < 2048) {
    conv8(Q, Qb, blk * 256 + tid, 1.f);
  } else if (blk < 4096) {
    conv8(KV, KVb, (blk - 2048) * 256 + tid, 1.f);
  } else if (blk < 4608) {
    conv8(Wq, Wqb, (blk - 4096) * 256 + tid, 0.125f);   // fold 1/8 into Wq
  } else if (blk < 5120) {
    conv8(Wk, Wkb, (blk - 4608) * 256 + tid, 1.f);
  } else if (blk < 5632) {
    conv8(Wv, Wvb, (blk - 5120) * 256 + tid, 1.f);
  } else if (blk < 6656) {
    // Wpb[o][g*64+d] = Wp[o][d*16+g]
    __shared__ float row[1024];
    const long o = blk - 5632;
    *(f32x4*)&row[tid * 4] = *(const f32x4*)(Wp + o * 1024 + tid * 4);
    __syncthreads();
    const int f0 = tid * 4;
    s16x4 t;
#pragma unroll
    for (int j = 0; j < 4; ++j) {
      int f = f0 + j;
      t[j] = f2bf(row[((f & 63) << 4) + (f >> 6)]);
    }
    *(s16x4*)(Wpb + o * 1024 + f0) = t;
  } else {
    int i = (blk - 6656) * 256 + tid;
    bqs[i] = bq[i] * 0.125f;                            // fold 1/8 into bq
  }
}

// ---------------- 128x128 GEMM core (BK=64, SINGLE-buffer, global_load_lds) ----------------
// m97-style: stage -> sync -> compute -> sync, 34.8 KB LDS -> 4 blocks/CU.
// Sm: 17408 shorts. Staging: A = Sm[0..8191], B = Sm[8192..16383].
// bf16 outputs bounce through Sm (stride 136) for coalesced 16B stores.
// omode 0: C[row*1024+col]; omode 1 (vt): C[col<<10 | t].
template <typename OutT>
static __device__ __forceinline__ void gemm_core(
    const short* __restrict__ A, const short* __restrict__ B,
    OutT* __restrict__ C, const float* __restrict__ bias,
    const float* __restrict__ resid, int bm, int bn, int omode,
    short* Sm) {
  const int tid = threadIdx.x, lane = tid & 63, wave = tid >> 6;
  const int fr = lane & 15, khi = lane >> 4;
  const int wr = wave >> 1, wc = wave & 1;

  f32x4 acc[4][4];
#pragma unroll
  for (int m = 0; m < 4; ++m)
#pragma unroll
    for (int n = 0; n < 4; ++n) acc[m][n] = (f32x4){0.f, 0.f, 0.f, 0.f};

  short* Asb = Sm;
  short* Bsb = Sm + 8192;
  for (int k0 = 0; k0 < 1024; k0 += 64) {
#pragma unroll
    for (int it = 0; it < 4; ++it) {
      int l = it * 256 + tid;
      int r = l >> 3, c = (l & 7) ^ (r & 7);
      gld16(A + (long)(bm + r) * 1024 + k0 + c * 8, &Asb[l * 8]);
      gld16(B + (long)(bn + r) * 1024 + k0 + c * 8, &Bsb[l * 8]);
    }
    __syncthreads();
#pragma unroll
    for (int ks = 0; ks < 64; ks += 32) {
      const int cc = (ks >> 3) + khi;
      short8 af[4], bf[4];
#pragma unroll
      for (int m = 0; m < 4; ++m) {
        const int ar = wr * 64 + m * 16 + fr;
        af[m] = *(const short8*)&Asb[ar * 64 + ((cc ^ (ar & 7)) * 8)];
      }
#pragma unroll
      for (int n = 0; n < 4; ++n) {
        const int br = wc * 64 + n * 16 + fr;
        bf[n] = *(const short8*)&Bsb[br * 64 + ((cc ^ (br & 7)) * 8)];
      }
#pragma unroll
      for (int m = 0; m < 4; ++m)
#pragma unroll
        for (int n = 0; n < 4; ++n)
          acc[m][n] = __builtin_amdgcn_mfma_f32_16x16x32_bf16(af[m], bf[n],
                                                              acc[m][n], 0, 0, 0);
    }
    __syncthreads();
  }

  const int col0 = fr, row0 = khi * 4;
  if constexpr (sizeof(OutT) == 2) {
    // bf16 output: LDS bounce (stride 136) -> coalesced 16B stores
#pragma unroll
    for (int m = 0; m < 4; ++m) {
#pragma unroll
      for (int n = 0; n < 4; ++n) {
        const int dgl = wc * 64 + n * 16 + col0;
        const float bi = bias[bn + dgl];
#pragma unroll
        for (int i = 0; i < 4; ++i) {
          const int tl = wr * 64 + m * 16 + row0 + i;
          const int a = (omode == 1) ? (dgl * 136 + tl) : (tl * 136 + dgl);
          Sm[a] = f2bf(acc[m][n][i] + bi);
        }
      }
    }
    __syncthreads();
    short* Cs = (short*)C;
#pragma unroll
    for (int it = 0; it < 8; ++it) {
      const int ch = it * 256 + tid;          // 2048 chunks of 16B
      const int r = ch >> 4, cchunk = ch & 15;
      short8 v8 = *(const short8*)&Sm[r * 136 + cchunk * 8];
      long addr;
      if (omode == 0)
        addr = (long)(bm + r) * 1024 + bn + cchunk * 8;
      else
        addr = ((long)(bm >> 10) << 20) + ((long)(bn + r) << 10) + (bm & 1023) +
               cchunk * 8;
      *(short8*)(Cs + addr) = v8;
    }
  } else {
    // f32 output (pre): scalar path, 64B segments
#pragma unroll
    for (int m = 0; m < 4; ++m) {
#pragma unroll
      for (int n = 0; n < 4; ++n) {
        const int gcol = bn + wc * 64 + n * 16 + col0;
        const float bi = bias[gcol];
#pragma unroll
        for (int i = 0; i < 4; ++i) {
          const int grow = bm + wr * 64 + m * 16 + row0 + i;
          float v = acc[m][n][i] + bi;
          if (resid) v += resid[(long)grow * 1024 + gcol];
          C[(long)grow * 1024 + gcol] = v;
        }
      }
    }
  }
}

// three projections in one launch: seg 0: qb, 1: kb, 2: vt
__global__ __launch_bounds__(256, 4) void proj_all(
    const short* __restrict__ Qb, const short* __restrict__ KVb,
    const short* __restrict__ Wqb, const short* __restrict__ Wkb,
    const short* __restrict__ Wvb,
    const float* __restrict__ bqs, const float* __restrict__ bk,
    const float* __restrict__ bv,
    short* __restrict__ qb, short* __restrict__ kb, short* __restrict__ vt) {
  __shared__ short Sm[17408];                // 34.8 KB -> 4 blocks/CU
  int bid = blockIdx.x;
  int swz = (bid & 7) * 96 + (bid >> 3);     // 768 blocks, XCD-contiguous
  const int seg = swz >> 8, local = swz & 255;
  const int bm = (local >> 3) * 128, bn = (local & 7) * 128;
  if (seg == 0)
    gemm_core<short>(Qb, Wqb, qb, bqs, nullptr, bm, bn, 0, Sm);
  else if (seg == 1)
    gemm_core<short>(KVb, Wkb, kb, bk, nullptr, bm, bn, 0, Sm);
  else
    gemm_core<short>(KVb, Wvb, vt, bv, nullptr, bm, bn, 1, Sm);
}

// final GEMM: pre = at @ Wpb^T + bp + Q
__global__ __launch_bounds__(256, 4) void out_gemm(
    const short* __restrict__ at, const short* __restrict__ Wpb,
    const float* __restrict__ bp, const float* __restrict__ Q,
    float* __restrict__ pre) {
  __shared__ short Sm[17408];
  int bid = blockIdx.x;
  int swz = (bid & 7) * 32 + (bid >> 3);     // 256 blocks
  const int bm = (swz >> 3) * 128, bn = (swz & 7) * 128;
  gemm_core<float>(at, Wpb, pre, bp, Q, bm, bn, 0, Sm);
}

// ---------------- fused attention (R14): 8 waves x 16 q-rows, dbuf ----------------
// Block = 512 thr (8 waves) per (z, 128 q-rows); wave owns 16 q-rows x all keys.
// K-feed permutation r2 = fr*4+nf (register-direct scores + packed Ps);
// K/V double-buffered. Grid 512 -> 2 blocks/CU = 16 waves/CU (LDS 50 KB).
__global__ __launch_bounds__(512, 4) void fused_attn(
    const short* __restrict__ qb,   // [4][1024][1024] bf16, feat = g*64+d (x1/8)
    const short* __restrict__ kb,   // [4][1024][1024] bf16, feat = g*64+d
    const short* __restrict__ vt,   // [4][1024][1024] bf16, vt[b][d*16+g][t]
    float* __restrict__ scores,     // [64][1024][1024] f32
    short* __restrict__ at) {       // [4][1024][1024] bf16, feat = g*64+d
  constexpr int LP = 72;
  __shared__ short Ks[2][64 * 64];  // 16 KB  (XOR key = (row>>2)&7)
  __shared__ short Vs[2][64 * 64];  // 16 KB  (XOR key = row&7)
  __shared__ short Ps[128 * LP];    // 18 KB  (wave-private 16-row slabs)

  int bid = blockIdx.x;
  bid = (bid & 7) * 64 + (bid >> 3);      // 8 z's per XCD
  const int z = bid >> 3, b = z >> 4, g = z & 15;
  const int q0 = (bid & 7) * 128;

  const int tid = threadIdx.x, lane = tid & 63, w = tid >> 6;
  const int fr = lane & 15, khi = lane >> 4;
  const long bqk = (long)b << 20;
  const int qr = q0 + w * 16;             // wave's 16 q rows

  const short* qrow = qb + bqk + (long)(qr + fr) * 1024 + g * 64 + khi * 8;
  const short8 aq0 = *(const short8*)qrow;
  const short8 aq1 = *(const short8*)(qrow + 32);
  const short* kgp = kb + bqk + g * 64;
  const short* vgp = vt + bqk;

  // 512 threads stage one 16B chunk each per 64x64 tile
  auto stageK = [&](int buf, int t0) {
    int r = tid >> 3, c = (tid & 7) ^ ((tid >> 5) & 7);
    gld16(kgp + (long)(t0 + r) * 1024 + c * 8, &Ks[buf][tid * 8]);
  };
  auto stageV = [&](int buf, int t0) {
    int r = tid >> 3, c = (tid & 7) ^ (r & 7);
    gld16(vgp + ((long)(r * 16 + g) << 10) + t0 + c * 8, &Vs[buf][tid * 8]);
  };

  const int xk = fr & 7;                  // Ks read XOR key: (r2>>2)&7, r2=fr*4+nf

  // ---- pass 1: exp-sums ----
  float s4[4] = {0.f, 0.f, 0.f, 0.f};
  stageK(0, 0);
  __syncthreads();
  int cur = 0;
  for (int t0 = 0; t0 < 1024; t0 += 64) {
    if (t0 < 960) stageK(cur ^ 1, t0 + 64);
    f32x4 sacc[4];
#pragma unroll
    for (int nf = 0; nf < 4; ++nf) sacc[nf] = (f32x4){0.f, 0.f, 0.f, 0.f};
#pragma unroll
    for (int nf = 0; nf < 4; ++nf) {
      const int r2 = fr * 4 + nf;
      short8 b0 = *(const short8*)&Ks[cur][r2 * 64 + ((khi ^ xk) * 8)];
      short8 b1 = *(const short8*)&Ks[cur][r2 * 64 + (((khi + 4) ^ xk) * 8)];
      sacc[nf] = __builtin_amdgcn_mfma_f32_16x16x32_bf16(aq0, b0, sacc[nf], 0, 0, 0);
      sacc[nf] = __builtin_amdgcn_mfma_f32_16x16x32_bf16(aq1, b1, sacc[nf], 0, 0, 0);
    }
#pragma unroll
    for (int nf = 0; nf < 4; ++nf)
#pragma unroll
      for (int i = 0; i < 4; ++i) s4[i] += __expf(sacc[nf][i]);
    __syncthreads();
    cur ^= 1;
  }
  float inv4[4];
#pragma unroll
  for (int i = 0; i < 4; ++i) {
    float s = s4[i];
    s += __shfl_xor(s, 1);
    s += __shfl_xor(s, 2);
    s += __shfl_xor(s, 4);
    s += __shfl_xor(s, 8);
    inv4[i] = 1.f / s;
  }

  // ---- pass 2: recompute, direct score store, packed Ps, PV ----
  f32x4 pacc[4];
#pragma unroll
  for (int nv = 0; nv < 4; ++nv) pacc[nv] = (f32x4){0.f, 0.f, 0.f, 0.f};

  stageK(0, 0);
  stageV(0, 0);
  __syncthreads();
  cur = 0;
  for (int t0 = 0; t0 < 1024; t0 += 64) {
    if (t0 < 960) {
      stageK(cur ^ 1, t0 + 64);
      stageV(cur ^ 1, t0 + 64);
    }
    f32x4 sacc[4];
#pragma unroll
    for (int nf = 0; nf < 4; ++nf) sacc[nf] = (f32x4){0.f, 0.f, 0.f, 0.f};
#pragma unroll
    for (int nf = 0; nf < 4; ++nf) {
      const int r2 = fr * 4 + nf;
      short8 b0 = *(const short8*)&Ks[cur][r2 * 64 + ((khi ^ xk) * 8)];
      short8 b1 = *(const short8*)&Ks[cur][r2 * 64 + (((khi + 4) ^ xk) * 8)];
      sacc[nf] = __builtin_amdgcn_mfma_f32_16x16x32_bf16(aq0, b0, sacc[nf], 0, 0, 0);
      sacc[nf] = __builtin_amdgcn_mfma_f32_16x16x32_bf16(aq1, b1, sacc[nf], 0, 0, 0);
    }
    // epilogue: lane holds keys fr*4+{0..3} for rows khi*4+i
#pragma unroll
    for (int i = 0; i < 4; ++i) {
      f32x4 o;
#pragma unroll
      for (int nf = 0; nf < 4; ++nf)
        o[nf] = __expf(sacc[nf][i]) * inv4[i];
      const int row = khi * 4 + i;
      __builtin_nontemporal_store(
          o, (f32x4*)&scores[((long)z << 20) + ((long)(qr + row) << 10) + t0 + fr * 4]);
      u32x2 pp;
      pp[0] = cvtpk(o[0], o[1]);
      pp[1] = cvtpk(o[2], o[3]);
      *(u32x2*)&Ps[(w * 16 + row) * LP + fr * 4] = pp;
    }

    // PV
#pragma unroll
    for (int ks = 0; ks < 64; ks += 32) {
      const int cc = (ks >> 3) + khi;
      short8 ap = *(const short8*)&Ps[(w * 16 + fr) * LP + ks + khi * 8];
#pragma unroll
      for (int nv = 0; nv < 4; ++nv) {
        const int dr = nv * 16 + fr;
        short8 bvv = *(const short8*)&Vs[cur][dr * 64 + ((cc ^ (dr & 7)) * 8)];
        pacc[nv] = __builtin_amdgcn_mfma_f32_16x16x32_bf16(ap, bvv, pacc[nv], 0, 0, 0);
      }
    }
    __syncthreads();
    cur ^= 1;
  }

  // at bounce via Ps (wave-private slab, no barrier needed)
#pragma unroll
  for (int nv = 0; nv < 4; ++nv)
#pragma unroll
    for (int i = 0; i < 4; ++i)
      Ps[(w * 16 + khi * 4 + i) * LP + nv * 16 + fr] = f2bf(pacc[nv][i]);
  const long atbase = bqk + ((long)qr << 10) + g * 64;
#pragma unroll
  for (int it = 0; it < 2; ++it) {
    const int ch = it * 64 + lane;          // 128 chunks: 16 rows x 8 chunks
    const int row = ch >> 3, fc = ch & 7;
    s16x4 lo = *(const s16x4*)&Ps[(w * 16 + row) * LP + fc * 8];
    s16x4 hi = *(const s16x4*)&Ps[(w * 16 + row) * LP + fc * 8 + 4];
    short8 v8;
    v8[0] = lo[0]; v8[1] = lo[1]; v8[2] = lo[2]; v8[3] = lo[3];
    v8[4] = hi[0]; v8[5] = hi[1]; v8[6] = hi[2]; v8[7] = hi[3];
    *(short8*)(at + atbase + ((long)row << 10) + fc * 8) = v8;
  }
}

// one wave per 1024-elem row
__global__ __launch_bounds__(256) void layernorm_rows(const float* __restrict__ X,
                                                      const float* __restrict__ gamma,
                                                      const float* __restrict__ beta,
                                                      float* __restrict__ O) {
  const int row = blockIdx.x * 4 + (threadIdx.x >> 6);
  const int lane = threadIdx.x & 63;
  const float* x = X + (long)row * 1024 + lane * 4;
  f32x4 v[4];
  float s = 0.f, sq = 0.f;
#pragma unroll
  for (int j = 0; j < 4; ++j) {
    v[j] = *(const f32x4*)(x + j * 256);
#pragma unroll
    for (int e = 0; e < 4; ++e) {
      s += v[j][e];
      sq += v[j][e] * v[j][e];
    }
  }
#pragma unroll
  for (int off = 32; off; off >>= 1) {
    s += __shfl_xor(s, off);
    sq += __shfl_xor(sq, off);
  }
  const float mu = s * (1.f / 1024.f);
  const float var = sq * (1.f / 1024.f) - mu * mu;
  const float rstd = rsqrtf(var + 1e-5f);
  float* o = O + (long)row * 1024 + lane * 4;
#pragma unroll
  for (int j = 0; j < 4; ++j) {
    f32x4 g = *(const f32x4*)(gamma + lane * 4 + j * 256);
    f32x4 be = *(const f32x4*)(beta + lane * 4 + j * 256);
    f32x4 r;
#pragma unroll
    for (int e = 0; e < 4; ++e) r[e] = (v[j][e] - mu) * rstd * g[e] + be[e];
    *(f32x4*)(o + j * 256) = r;
  }
}

extern "C" void kernel_launch(void* const* d_in, const int* in_sizes, int n_in,
                              void* d_out, int out_size, void* d_ws, size_t ws_size,
                              hipStream_t stream) {
  const float* Q = (const float*)d_in[0];
  const float* KV = (const float*)d_in[1];
  const float* Wq = (const float*)d_in[2];
  const float* bq = (const float*)d_in[3];
  const float* Wk = (const float*)d_in[4];
  const float* bk = (const float*)d_in[5];
  const float* Wv = (const float*)d_in[6];
  const float* bv = (const float*)d_in[7];
  const float* Wp = (const float*)d_in[8];
  const float* bp = (const float*)d_in[9];
  const float* gamma = (const float*)d_in[10];
  const float* beta = (const float*)d_in[11];

  float* out = (float*)d_out;                       // [4M] f32
  float* scores = out + (long)4 * 1024 * 1024;      // [64M] f32

  char* ws = (char*)d_ws;
  short* Wqb = (short*)(ws);                        // 2MB each
  short* Wkb = (short*)(ws + (2L << 20));
  short* Wvb = (short*)(ws + (4L << 20));
  short* Wpb = (short*)(ws + (6L << 20));           // permuted columns
  short* qb  = (short*)(ws + (8L << 20));           // 8MB (pre-scaled by 1/8)
  short* kb  = (short*)(ws + (16L << 20));          // 8MB
  short* vt  = (short*)(ws + (24L << 20));          // 8MB
  short* at  = (short*)(ws + (32L << 20));          // 8MB, feat = g*64+d
  float* pre = (float*)(ws + (40L << 20));          // 16MB (written after attn)
  short* Qb  = (short*)(ws + (40L << 20));          // 8MB  (dead before pre)
  short* KVb = (short*)(ws + (48L << 20));          // 8MB  (dead before pre)
  float* bqs = (float*)(ws + (56L << 20));          // 4KB
  (void)ws_size; (void)in_sizes; (void)n_in; (void)out_size;

  // 1) all conversions, one launch
  prep<<<6660, 256, 0, stream>>>(Q, KV, Wq, Wk, Wv, Wp, bq,
                                 Qb, KVb, Wqb, Wkb, Wvb, Wpb, bqs);

  // 2) three projections, one launch
  proj_all<<<768, 256, 0, stream>>>(Qb, KVb, Wqb, Wkb, Wvb, bqs, bk, bv,
                                    qb, kb, vt);

  // 3) fused attention: scores (d_out) + at
  fused_attn<<<512, 512, 0, stream>>>(qb, kb, vt, scores, at);

  // 4) pre = at @ Wpb^T + bp + Q
  out_gemm<<<256, 256, 0, stream>>>(at, Wpb, bp, Q, pre);

  // 5) LayerNorm -> out
  layernorm_rows<<<1024, 256, 0, stream>>>(pre, gamma, beta, out);
}

// Round 19
// 161.460 us; speedup vs baseline: 1.0806x; 1.0202x over previous
//
#include <hip/hip_runtime.h>

typedef __attribute__((ext_vector_type(8))) short short8;
typedef __attribute__((ext_vector_type(4))) short s16x4;
typedef __attribute__((ext_vector_type(4))) float f32x4;
typedef __attribute__((ext_vector_type(2))) unsigned u32x2;

static __device__ __forceinline__ short f2bf(float x) {
  union { float f; unsigned u; } v; v.f = x;
  unsigned r = (v.u + 0x7fffu + ((v.u >> 16) & 1u)) >> 16;
  return (short)r;
}
// packed f32x2 -> bf16x2 (RNE), 1 VALU op
static __device__ __forceinline__ unsigned cvtpk(float lo, float hi) {
  unsigned r;
  asm("v_cvt_pk_bf16_f32 %0, %1, %2" : "=v"(r) : "v"(lo), "v"(hi));
  return r;
}

// async 16B global -> LDS (dest: wave-uniform base + lane*16; src: per-lane)
static __device__ __forceinline__ void gld16(const short* g, short* l) {
  __builtin_amdgcn_global_load_lds(
      (const __attribute__((address_space(1))) unsigned*)g,
      (__attribute__((address_space(3))) unsigned*)l, 16, 0, 0);
}

// ---------------- prep: all conversions in one launch ----------------
static __device__ __forceinline__ void conv8(const float* __restrict__ src,
                                             short* __restrict__ dst, int i,
                                             float scale) {
  const f32x4* s = (const f32x4*)(src + (long)i * 8);
  f32x4 a = s[0], b = s[1];
  short8 o;
  o[0] = f2bf(a[0] * scale); o[1] = f2bf(a[1] * scale);
  o[2] = f2bf(a[2] * scale); o[3] = f2bf(a[3] * scale);
  o[4] = f2bf(b[0] * scale); o[5] = f2bf(b[1] * scale);
  o[6] = f2bf(b[2] * scale); o[7] = f2bf(b[3] * scale);
  *(short8*)(dst + (long)i * 8) = o;
}

__global__ __launch_bounds__(256) void prep(
    const float* __restrict__ Q, const float* __restrict__ KV,
    const float* __restrict__ Wq, const float* __restrict__ Wk,
    const float* __restrict__ Wv, const float* __restrict__ Wp,
    const float* __restrict__ bq,
    short* __restrict__ Qb, short* __restrict__ KVb,
    short* __restrict__ Wqb, short* __restrict__ Wkb,
    short* __restrict__ Wvb, short* __restrict__ Wpb,
    float* __restrict__ bqs) {
  const int blk = blockIdx.x, tid = threadIdx.x;
  if (blk < 2048) {
    conv8(Q, Qb, blk * 256 + tid, 1.f);
  } else if (blk < 4096) {
    conv8(KV, KVb, (blk - 2048) * 256 + tid, 1.f);
  } else if (blk < 4608) {
    conv8(Wq, Wqb, (blk - 4096) * 256 + tid, 0.125f);   // fold 1/8 into Wq
  } else if (blk < 5120) {
    conv8(Wk, Wkb, (blk - 4608) * 256 + tid, 1.f);
  } else if (blk < 5632) {
    conv8(Wv, Wvb, (blk - 5120) * 256 + tid, 1.f);
  } else if (blk < 6656) {
    // Wpb[o][g*64+d] = Wp[o][d*16+g]
    __shared__ float row[1024];
    const long o = blk - 5632;
    *(f32x4*)&row[tid * 4] = *(const f32x4*)(Wp + o * 1024 + tid * 4);
    __syncthreads();
    const int f0 = tid * 4;
    s16x4 t;
#pragma unroll
    for (int j = 0; j < 4; ++j) {
      int f = f0 + j;
      t[j] = f2bf(row[((f & 63) << 4) + (f >> 6)]);
    }
    *(s16x4*)(Wpb + o * 1024 + f0) = t;
  } else {
    int i = (blk - 6656) * 256 + tid;
    bqs[i] = bq[i] * 0.125f;                            // fold 1/8 into bq
  }
}

// ---------------- 128x128 GEMM core (BK=64, dbuf, global_load_lds) ----------------
// Sm: 32768-short flat LDS. bf16 outputs bounce through LDS (stride 136) for
// coalesced 16B stores. omode 0: C[row*1024+col]; omode 1 (vt): C[col<<10 | t].
template <typename OutT>
static __device__ __forceinline__ void gemm_core(
    const short* __restrict__ A, const short* __restrict__ B,
    OutT* __restrict__ C, const float* __restrict__ bias,
    const float* __restrict__ resid, int bm, int bn, int omode,
    short* Sm) {
  const int tid = threadIdx.x, lane = tid & 63, wave = tid >> 6;
  const int fr = lane & 15, khi = lane >> 4;
  const int wr = wave >> 1, wc = wave & 1;

  f32x4 acc[4][4];
#pragma unroll
  for (int m = 0; m < 4; ++m)
#pragma unroll
    for (int n = 0; n < 4; ++n) acc[m][n] = (f32x4){0.f, 0.f, 0.f, 0.f};

  auto stage = [&](int buf, int k0) {
    short* Asb = Sm + buf * 16384;
    short* Bsb = Asb + 8192;
#pragma unroll
    for (int it = 0; it < 4; ++it) {
      int l = it * 256 + tid;
      int r = l >> 3, c = (l & 7) ^ (r & 7);
      gld16(A + (long)(bm + r) * 1024 + k0 + c * 8, &Asb[l * 8]);
      gld16(B + (long)(bn + r) * 1024 + k0 + c * 8, &Bsb[l * 8]);
    }
  };

  stage(0, 0);
  __syncthreads();
  int cur = 0;
  for (int k0 = 0; k0 < 1024; k0 += 64) {
    if (k0 < 960) stage(cur ^ 1, k0 + 64);
    const short* Asb = Sm + cur * 16384;
    const short* Bsb = Asb + 8192;
#pragma unroll
    for (int ks = 0; ks < 64; ks += 32) {
      const int cc = (ks >> 3) + khi;
      short8 af[4], bf[4];
#pragma unroll
      for (int m = 0; m < 4; ++m) {
        const int ar = wr * 64 + m * 16 + fr;
        af[m] = *(const short8*)&Asb[ar * 64 + ((cc ^ (ar & 7)) * 8)];
      }
#pragma unroll
      for (int n = 0; n < 4; ++n) {
        const int br = wc * 64 + n * 16 + fr;
        bf[n] = *(const short8*)&Bsb[br * 64 + ((cc ^ (br & 7)) * 8)];
      }
#pragma unroll
      for (int m = 0; m < 4; ++m)
#pragma unroll
        for (int n = 0; n < 4; ++n)
          acc[m][n] = __builtin_amdgcn_mfma_f32_16x16x32_bf16(af[m], bf[n],
                                                              acc[m][n], 0, 0, 0);
    }
    __syncthreads();
    cur ^= 1;
  }

  const int col0 = fr, row0 = khi * 4;
  if constexpr (sizeof(OutT) == 2) {
    // bf16 output: LDS bounce -> coalesced 16B stores
#pragma unroll
    for (int m = 0; m < 4; ++m) {
#pragma unroll
      for (int n = 0; n < 4; ++n) {
        const int dgl = wc * 64 + n * 16 + col0;
        const float bi = bias[bn + dgl];
#pragma unroll
        for (int i = 0; i < 4; ++i) {
          const int tl = wr * 64 + m * 16 + row0 + i;
          const int a = (omode == 1) ? (dgl * 136 + tl) : (tl * 136 + dgl);
          Sm[a] = f2bf(acc[m][n][i] + bi);
        }
      }
    }
    __syncthreads();
    short* Cs = (short*)C;
#pragma unroll
    for (int it = 0; it < 8; ++it) {
      const int ch = it * 256 + tid;          // 2048 chunks of 16B
      const int r = ch >> 4, cchunk = ch & 15;
      short8 v8 = *(const short8*)&Sm[r * 136 + cchunk * 8];
      long addr;
      if (omode == 0)
        addr = (long)(bm + r) * 1024 + bn + cchunk * 8;
      else
        addr = ((long)(bm >> 10) << 20) + ((long)(bn + r) << 10) + (bm & 1023) +
               cchunk * 8;
      *(short8*)(Cs + addr) = v8;
    }
  } else {
    // f32 output (pre): scalar path, 64B segments
#pragma unroll
    for (int m = 0; m < 4; ++m) {
#pragma unroll
      for (int n = 0; n < 4; ++n) {
        const int gcol = bn + wc * 64 + n * 16 + col0;
        const float bi = bias[gcol];
#pragma unroll
        for (int i = 0; i < 4; ++i) {
          const int grow = bm + wr * 64 + m * 16 + row0 + i;
          float v = acc[m][n][i] + bi;
          if (resid) v += resid[(long)grow * 1024 + gcol];
          C[(long)grow * 1024 + gcol] = v;
        }
      }
    }
  }
}

// three projections in one launch: seg 0: qb, 1: kb, 2: vt
__global__ __launch_bounds__(256, 2) void proj_all(
    const short* __restrict__ Qb, const short* __restrict__ KVb,
    const short* __restrict__ Wqb, const short* __restrict__ Wkb,
    const short* __restrict__ Wvb,
    const float* __restrict__ bqs, const float* __restrict__ bk,
    const float* __restrict__ bv,
    short* __restrict__ qb, short* __restrict__ kb, short* __restrict__ vt) {
  __shared__ short Sm[32768];                // 64 KB
  int bid = blockIdx.x;
  int swz = (bid & 7) * 96 + (bid >> 3);     // 768 blocks, XCD-contiguous
  const int seg = swz >> 8, local = swz & 255;
  const int bm = (local >> 3) * 128, bn = (local & 7) * 128;
  if (seg == 0)
    gemm_core<short>(Qb, Wqb, qb, bqs, nullptr, bm, bn, 0, Sm);
  else if (seg == 1)
    gemm_core<short>(KVb, Wkb, kb, bk, nullptr, bm, bn, 0, Sm);
  else
    gemm_core<short>(KVb, Wvb, vt, bv, nullptr, bm, bn, 1, Sm);
}

// final GEMM: pre = at @ Wpb^T + bp + Q
__global__ __launch_bounds__(256, 2) void out_gemm(
    const short* __restrict__ at, const short* __restrict__ Wpb,
    const float* __restrict__ bp, const float* __restrict__ Q,
    float* __restrict__ pre) {
  __shared__ short Sm[32768];
  int bid = blockIdx.x;
  int swz = (bid & 7) * 32 + (bid >> 3);     // 256 blocks
  const int bm = (swz >> 3) * 128, bn = (swz & 7) * 128;
  gemm_core<float>(at, Wpb, pre, bp, Q, bm, bn, 0, Sm);
}

// ---------------- fused attention (R14): 8 waves x 16 q-rows, dbuf ----------------
// Block = 512 thr (8 waves) per (z, 128 q-rows); wave owns 16 q-rows x all keys.
// K-feed permutation r2 = fr*4+nf (register-direct scores + packed Ps);
// K/V double-buffered. Grid 512 -> 2 blocks/CU = 16 waves/CU (LDS 50 KB).
__global__ __launch_bounds__(512, 4) void fused_attn(
    const short* __restrict__ qb,   // [4][1024][1024] bf16, feat = g*64+d (x1/8)
    const short* __restrict__ kb,   // [4][1024][1024] bf16, feat = g*64+d
    const short* __restrict__ vt,   // [4][1024][1024] bf16, vt[b][d*16+g][t]
    float* __restrict__ scores,     // [64][1024][1024] f32
    short* __restrict__ at) {       // [4][1024][1024] bf16, feat = g*64+d
  constexpr int LP = 72;
  __shared__ short Ks[2][64 * 64];  // 16 KB  (XOR key = (row>>2)&7)
  __shared__ short Vs[2][64 * 64];  // 16 KB  (XOR key = row&7)
  __shared__ short Ps[128 * LP];    // 18 KB  (wave-private 16-row slabs)

  int bid = blockIdx.x;
  bid = (bid & 7) * 64 + (bid >> 3);      // 8 z's per XCD
  const int z = bid >> 3, b = z >> 4, g = z & 15;
  const int q0 = (bid & 7) * 128;

  const int tid = threadIdx.x, lane = tid & 63, w = tid >> 6;
  const int fr = lane & 15, khi = lane >> 4;
  const long bqk = (long)b << 20;
  const int qr = q0 + w * 16;             // wave's 16 q rows

  const short* qrow = qb + bqk + (long)(qr + fr) * 1024 + g * 64 + khi * 8;
  const short8 aq0 = *(const short8*)qrow;
  const short8 aq1 = *(const short8*)(qrow + 32);
  const short* kgp = kb + bqk + g * 64;
  const short* vgp = vt + bqk;

  // 512 threads stage one 16B chunk each per 64x64 tile
  auto stageK = [&](int buf, int t0) {
    int r = tid >> 3, c = (tid & 7) ^ ((tid >> 5) & 7);
    gld16(kgp + (long)(t0 + r) * 1024 + c * 8, &Ks[buf][tid * 8]);
  };
  auto stageV = [&](int buf, int t0) {
    int r = tid >> 3, c = (tid & 7) ^ (r & 7);
    gld16(vgp + ((long)(r * 16 + g) << 10) + t0 + c * 8, &Vs[buf][tid * 8]);
  };

  const int xk = fr & 7;                  // Ks read XOR key: (r2>>2)&7, r2=fr*4+nf

  // ---- pass 1: exp-sums ----
  float s4[4] = {0.f, 0.f, 0.f, 0.f};
  stageK(0, 0);
  __syncthreads();
  int cur = 0;
  for (int t0 = 0; t0 < 1024; t0 += 64) {
    if (t0 < 960) stageK(cur ^ 1, t0 + 64);
    f32x4 sacc[4];
#pragma unroll
    for (int nf = 0; nf < 4; ++nf) sacc[nf] = (f32x4){0.f, 0.f, 0.f, 0.f};
#pragma unroll
    for (int nf = 0; nf < 4; ++nf) {
      const int r2 = fr * 4 + nf;
      short8 b0 = *(const short8*)&Ks[cur][r2 * 64 + ((khi ^ xk) * 8)];
      short8 b1 = *(const short8*)&Ks[cur][r2 * 64 + (((khi + 4) ^ xk) * 8)];
      sacc[nf] = __builtin_amdgcn_mfma_f32_16x16x32_bf16(aq0, b0, sacc[nf], 0, 0, 0);
      sacc[nf] = __builtin_amdgcn_mfma_f32_16x16x32_bf16(aq1, b1, sacc[nf], 0, 0, 0);
    }
#pragma unroll
    for (int nf = 0; nf < 4; ++nf)
#pragma unroll
      for (int i = 0; i < 4; ++i) s4[i] += __expf(sacc[nf][i]);
    __syncthreads();
    cur ^= 1;
  }
  float inv4[4];
#pragma unroll
  for (int i = 0; i < 4; ++i) {
    float s = s4[i];
    s += __shfl_xor(s, 1);
    s += __shfl_xor(s, 2);
    s += __shfl_xor(s, 4);
    s += __shfl_xor(s, 8);
    inv4[i] = 1.f / s;
  }

  // ---- pass 2: recompute, direct score store, packed Ps, PV ----
  f32x4 pacc[4];
#pragma unroll
  for (int nv = 0; nv < 4; ++nv) pacc[nv] = (f32x4){0.f, 0.f, 0.f, 0.f};

  stageK(0, 0);
  stageV(0, 0);
  __syncthreads();
  cur = 0;
  for (int t0 = 0; t0 < 1024; t0 += 64) {
    if (t0 < 960) {
      stageK(cur ^ 1, t0 + 64);
      stageV(cur ^ 1, t0 + 64);
    }
    f32x4 sacc[4];
#pragma unroll
    for (int nf = 0; nf < 4; ++nf) sacc[nf] = (f32x4){0.f, 0.f, 0.f, 0.f};
#pragma unroll
    for (int nf = 0; nf < 4; ++nf) {
      const int r2 = fr * 4 + nf;
      short8 b0 = *(const short8*)&Ks[cur][r2 * 64 + ((khi ^ xk) * 8)];
      short8 b1 = *(const short8*)&Ks[cur][r2 * 64 + (((khi + 4) ^ xk) * 8)];
      sacc[nf] = __builtin_amdgcn_mfma_f32_16x16x32_bf16(aq0, b0, sacc[nf], 0, 0, 0);
      sacc[nf] = __builtin_amdgcn_mfma_f32_16x16x32_bf16(aq1, b1, sacc[nf], 0, 0, 0);
    }
    // epilogue: lane holds keys fr*4+{0..3} for rows khi*4+i
#pragma unroll
    for (int i = 0; i < 4; ++i) {
      f32x4 o;
#pragma unroll
      for (int nf = 0; nf < 4; ++nf)
        o[nf] = __expf(sacc[nf][i]) * inv4[i];
      const int row = khi * 4 + i;
      __builtin_nontemporal_store(
          o, (f32x4*)&scores[((long)z << 20) + ((long)(qr + row) << 10) + t0 + fr * 4]);
      u32x2 pp;
      pp[0] = cvtpk(o[0], o[1]);
      pp[1] = cvtpk(o[2], o[3]);
      *(u32x2*)&Ps[(w * 16 + row) * LP + fr * 4] = pp;
    }

    // PV
#pragma unroll
    for (int ks = 0; ks < 64; ks += 32) {
      const int cc = (ks >> 3) + khi;
      short8 ap = *(const short8*)&Ps[(w * 16 + fr) * LP + ks + khi * 8];
#pragma unroll
      for (int nv = 0; nv < 4; ++nv) {
        const int dr = nv * 16 + fr;
        short8 bvv = *(const short8*)&Vs[cur][dr * 64 + ((cc ^ (dr & 7)) * 8)];
        pacc[nv] = __builtin_amdgcn_mfma_f32_16x16x32_bf16(ap, bvv, pacc[nv], 0, 0, 0);
      }
    }
    __syncthreads();
    cur ^= 1;
  }

  // at bounce via Ps (wave-private slab, no barrier needed)
#pragma unroll
  for (int nv = 0; nv < 4; ++nv)
#pragma unroll
    for (int i = 0; i < 4; ++i)
      Ps[(w * 16 + khi * 4 + i) * LP + nv * 16 + fr] = f2bf(pacc[nv][i]);
  const long atbase = bqk + ((long)qr << 10) + g * 64;
#pragma unroll
  for (int it = 0; it < 2; ++it) {
    const int ch = it * 64 + lane;          // 128 chunks: 16 rows x 8 chunks
    const int row = ch >> 3, fc = ch & 7;
    s16x4 lo = *(const s16x4*)&Ps[(w * 16 + row) * LP + fc * 8];
    s16x4 hi = *(const s16x4*)&Ps[(w * 16 + row) * LP + fc * 8 + 4];
    short8 v8;
    v8[0] = lo[0]; v8[1] = lo[1]; v8[2] = lo[2]; v8[3] = lo[3];
    v8[4] = hi[0]; v8[5] = hi[1]; v8[6] = hi[2]; v8[7] = hi[3];
    *(short8*)(at + atbase + ((long)row << 10) + fc * 8) = v8;
  }
}

// one wave per 1024-elem row
__global__ __launch_bounds__(256) void layernorm_rows(const float* __restrict__ X,
                                                      const float* __restrict__ gamma,
                                                      const float* __restrict__ beta,
                                                      float* __restrict__ O) {
  const int row = blockIdx.x * 4 + (threadIdx.x >> 6);
  const int lane = threadIdx.x & 63;
  const float* x = X + (long)row * 1024 + lane * 4;
  f32x4 v[4];
  float s = 0.f, sq = 0.f;
#pragma unroll
  for (int j = 0; j < 4; ++j) {
    v[j] = *(const f32x4*)(x + j * 256);
#pragma unroll
    for (int e = 0; e < 4; ++e) {
      s += v[j][e];
      sq += v[j][e] * v[j][e];
    }
  }
#pragma unroll
  for (int off = 32; off; off >>= 1) {
    s += __shfl_xor(s, off);
    sq += __shfl_xor(sq, off);
  }
  const float mu = s * (1.f / 1024.f);
  const float var = sq * (1.f / 1024.f) - mu * mu;
  const float rstd = rsqrtf(var + 1e-5f);
  float* o = O + (long)row * 1024 + lane * 4;
#pragma unroll
  for (int j = 0; j < 4; ++j) {
    f32x4 g = *(const f32x4*)(gamma + lane * 4 + j * 256);
    f32x4 be = *(const f32x4*)(beta + lane * 4 + j * 256);
    f32x4 r;
#pragma unroll
    for (int e = 0; e < 4; ++e) r[e] = (v[j][e] - mu) * rstd * g[e] + be[e];
    *(f32x4*)(o + j * 256) = r;
  }
}

extern "C" void kernel_launch(void* const* d_in, const int* in_sizes, int n_in,
                              void* d_out, int out_size, void* d_ws, size_t ws_size,
                              hipStream_t stream) {
  const float* Q = (const float*)d_in[0];
  const float* KV = (const float*)d_in[1];
  const float* Wq = (const float*)d_in[2];
  const float* bq = (const float*)d_in[3];
  const float* Wk = (const float*)d_in[4];
  const float* bk = (const float*)d_in[5];
  const float* Wv = (const float*)d_in[6];
  const float* bv = (const float*)d_in[7];
  const float* Wp = (const float*)d_in[8];
  const float* bp = (const float*)d_in[9];
  const float* gamma = (const float*)d_in[10];
  const float* beta = (const float*)d_in[11];

  float* out = (float*)d_out;                       // [4M] f32
  float* scores = out + (long)4 * 1024 * 1024;      // [64M] f32

  char* ws = (char*)d_ws;
  short* Wqb = (short*)(ws);                        // 2MB each
  short* Wkb = (short*)(ws + (2L << 20));
  short* Wvb = (short*)(ws + (4L << 20));
  short* Wpb = (short*)(ws + (6L << 20));           // permuted columns
  short* qb  = (short*)(ws + (8L << 20));           // 8MB (pre-scaled by 1/8)
  short* kb  = (short*)(ws + (16L << 20));          // 8MB
  short* vt  = (short*)(ws + (24L << 20));          // 8MB
  short* at  = (short*)(ws + (32L << 20));          // 8MB, feat = g*64+d
  float* pre = (float*)(ws + (40L << 20));          // 16MB (written after attn)
  short* Qb  = (short*)(ws + (40L << 20));          // 8MB  (dead before pre)
  short* KVb = (short*)(ws + (48L << 20));          // 8MB  (dead before pre)
  float* bqs = (float*)(ws + (56L << 20));          // 4KB
  (void)ws_size; (void)in_sizes; (void)n_in; (void)out_size;

  // 1) all conversions, one launch
  prep<<<6660, 256, 0, stream>>>(Q, KV, Wq, Wk, Wv, Wp, bq,
                                 Qb, KVb, Wqb, Wkb, Wvb, Wpb, bqs);

  // 2) three projections, one launch
  proj_all<<<768, 256, 0, stream>>>(Qb, KVb, Wqb, Wkb, Wvb, bqs, bk, bv,
                                    qb, kb, vt);

  // 3) fused attention: scores (d_out) + at
  fused_attn<<<512, 512, 0, stream>>>(qb, kb, vt, scores, at);

  // 4) pre = at @ Wpb^T + bp + Q
  out_gemm<<<256, 256, 0, stream>>>(at, Wpb, bp, Q, pre);

  // 5) LayerNorm -> out
  layernorm_rows<<<1024, 256, 0, stream>>>(pre, gamma, beta, out);
}